// Round 9
// baseline (83.911 us; speedup 1.0000x reference)
//
#include <hip/hip_runtime.h>
#include <hip/hip_bf16.h>
#include <math.h>

// ---------------- problem constants ----------------
namespace {
constexpr int BATCH = 4;
constexpr int IMG   = 192;
constexpr int PL    = IMG * IMG;   // 36864
constexpr int NP1   = 4096;   // 64*64 full-res patches per image
constexpr int MALL  = 5376;   // 4096 + 1024 + 256 candidate patches
constexpr int RS    = 28;     // fp32 row stride: 27 values + |c|^2 slot
constexpr int NCHUNK = 21;    // m-chunks for argmin partials
constexpr int TPC    = 16;    // 16-wide m-tiles per chunk (21*16*16 = 5376)
constexpr int RPT    = 4;     // tiles staged per barrier round
constexpr int ROUNDS = TPC / RPT;  // 4
constexpr int NROWS  = BATCH * NP1;  // 16384

// gaussian kernel constants (float32 images of the numpy float32 values)
#define GA 0.27406862f   // gauss1d(1.0) edge
#define GB 0.45186276f   // gauss1d(1.0) center
#define RC 0.33277732f   // gauss1d(10.0) edge
#define RD 0.33444537f   // gauss1d(10.0) center

typedef __bf16 bf16x8 __attribute__((ext_vector_type(8)));
typedef float  f32x4  __attribute__((ext_vector_type(4)));

__device__ __forceinline__ void conv3(const float in[9], const float k[9], float out[9]) {
#pragma unroll
  for (int y = 0; y < 3; ++y)
#pragma unroll
    for (int x = 0; x < 3; ++x) {
      float s = 0.f;
#pragma unroll
      for (int i = 0; i < 3; ++i) {
        int yy = y + i - 1;
        if (yy < 0 || yy > 2) continue;
#pragma unroll
        for (int j = 0; j < 3; ++j) {
          int xx = x + j - 1;
          if (xx < 0 || xx > 2) continue;
          s = fmaf(k[i * 3 + j], in[yy * 3 + xx], s);
        }
      }
      out[y * 3 + x] = s;
    }
}

// gray -> normalized structure-tensor 27-vector + |c|^2 of the normalized vec
__device__ __forceinline__ void st_from_gray(const float gray[9], float stv[27], float& cs) {
  const float KX[9] = {GA * GA, 0.f, -GA * GA, GB * GA, 0.f, -GB * GA, GA * GA, 0.f, -GA * GA};
  const float KY[9] = {GA * GA, GA * GB, GA * GA, 0.f, 0.f, 0.f, -GA * GA, -GA * GB, -GA * GA};
  const float KS[9] = {RC * RC, RC * RD, RC * RC, RD * RC, RD * RD, RD * RC, RC * RC, RC * RD, RC * RC};
  float Ix[9], Iy[9];
  conv3(gray, KX, Ix);
  conv3(gray, KY, Iy);
  float Pxx[9], Pyy[9], Pxy[9];
#pragma unroll
  for (int t = 0; t < 9; ++t) {
    Pxx[t] = Ix[t] * Ix[t];
    Pyy[t] = Iy[t] * Iy[t];
    Pxy[t] = Ix[t] * Iy[t];
  }
  conv3(Pxx, KS, stv + 0);
  conv3(Pyy, KS, stv + 9);
  conv3(Pxy, KS, stv + 18);
  float s2 = 0.f;
#pragma unroll
  for (int d = 0; d < 27; ++d) s2 = fmaf(stv[d], stv[d], s2);
  float inv = 1.0f / (sqrtf(s2) + 1e-12f);
  float c = 0.f;
#pragma unroll
  for (int d = 0; d < 27; ++d) {
    stv[d] *= inv;
    c = fmaf(stv[d], stv[d], c);
  }
  cs = c;
}

// ---------------- bicubic taps (jax.image.resize, antialias=False) ----------------
__device__ __forceinline__ void mkw(int k0, int IS, float w[4], int k[4]) {
  const float W4[4] = {-0.0625f, 0.5625f, 0.5625f, -0.0625f};
  float ssum = 0.f;
#pragma unroll
  for (int u = 0; u < 4; ++u) {
    int kk = k0 + u;
    bool v = (kk >= 0) && (kk < IS);
    w[u] = v ? W4[u] : 0.f;
    k[u] = v ? kk : 0;
    ssum += w[u];
  }
  float inv = 1.f / ssum;  // interior: exactly 1.0
#pragma unroll
  for (int u = 0; u < 4; ++u) w[u] *= inv;
}

// ---------------- fragment-major bf16 hi/lo pack ----------------
// Tile = 16 rows = 512 uints (2 KB): hi half uints 0..255, lo half 256..511.
// Row rl, k-group lg -> uint4 at (lg*16+rl)*4 (hi) / 256+(lg*16+rl)*4 (lo).
// In argmin, lane l reads uint4 at tile_base + l*4 -> fully coalesced.
__device__ __forceinline__ void pack_row_frag(const float* __restrict__ v, float tail,
                                              unsigned* __restrict__ base, int rl) {
  unsigned uh[16], ul[16];
#pragma unroll
  for (int p = 0; p < 16; ++p) {
    float a  = (2 * p < 27) ? v[2 * p] : 0.f;
    float bb = (2 * p + 1 < 27) ? v[2 * p + 1] : (2 * p + 1 == 27 ? tail : 0.f);
    __hip_bfloat16 ah = __float2bfloat16(a);
    __hip_bfloat16 bh = __float2bfloat16(bb);
    float af = __bfloat162float(ah), bf2 = __bfloat162float(bh);
    __hip_bfloat16 al = __float2bfloat16(a - af);
    __hip_bfloat16 bl = __float2bfloat16(bb - bf2);
    uh[p] = ((unsigned)__builtin_bit_cast(unsigned short, bh) << 16) |
            (unsigned)__builtin_bit_cast(unsigned short, ah);
    ul[p] = ((unsigned)__builtin_bit_cast(unsigned short, bl) << 16) |
            (unsigned)__builtin_bit_cast(unsigned short, al);
  }
#pragma unroll
  for (int lg = 0; lg < 4; ++lg) {
    *reinterpret_cast<uint4*>(base + (size_t)(lg * 16 + rl) * 4) =
        make_uint4(uh[4 * lg], uh[4 * lg + 1], uh[4 * lg + 2], uh[4 * lg + 3]);
    *reinterpret_cast<uint4*>(base + 256 + (size_t)(lg * 16 + rl) * 4) =
        make_uint4(ul[4 * lg], ul[4 * lg + 1], ul[4 * lg + 2], ul[4 * lg + 3]);
  }
}

__device__ __forceinline__ void store_row28(float* __restrict__ dst, const float v[27], float tail) {
  float4* d4 = reinterpret_cast<float4*>(dst);
#pragma unroll
  for (int i = 0; i < 6; ++i)
    d4[i] = make_float4(v[4 * i], v[4 * i + 1], v[4 * i + 2], v[4 * i + 3]);
  d4[6] = make_float4(v[24], v[25], v[26], tail);
}

// ---------------- K0: grayscale planes for x and gt (coalesced) ----------------
__global__ void __launch_bounds__(256) gray_kernel(
    const float* __restrict__ x, const float* __restrict__ gt,
    float* __restrict__ gx, float* __restrict__ ggt, unsigned* __restrict__ ctr) {
  int o = blockIdx.x * 256 + threadIdx.x;  // [0, 2*BATCH*PL)
  if (o == 0) ctr[0] = 0;                  // reset finalize ticket (stream-ordered)
  const float* src;
  float* dst;
  int oo;
  if (o < BATCH * PL) { src = x; dst = gx; oo = o; }
  else                { src = gt; dst = ggt; oo = o - BATCH * PL; }
  int b = oo / PL, p = oo - b * PL;
  const float* im = src + (size_t)b * 3 * PL;
  dst[oo] = fmaf(0.114f, im[2 * PL + p], fmaf(0.587f, im[PL + p], 0.2989f * im[p]));
}

// ---------------- K0b: bicubic resize of the gt gray plane (96 and 48) ------------
// Same tap order as the validated bicubic_gray (gray commutes with resize).
__global__ void __launch_bounds__(256) resize_gray_kernel(
    const float* __restrict__ ggt, float* __restrict__ g96, float* __restrict__ g48) {
  int o = blockIdx.x * 256 + threadIdx.x;  // [0, 46080)
  int i, j, S, step, koff;
  const float* src;
  float* dst;
  int oo;
  if (o < BATCH * 9216) {
    int b = o / 9216, rem = o - b * 9216;
    i = rem / 96; j = rem - i * 96;
    S = 96; step = 2; koff = -1;
    src = ggt + (size_t)b * PL;
    dst = g96; oo = o;
  } else {
    int q = o - BATCH * 9216;
    int b = q / 2304, rem = q - b * 2304;
    i = rem / 48; j = rem - i * 48;
    S = 48; step = 4; koff = 0;
    src = ggt + (size_t)b * PL;
    dst = g48; oo = q;
  }
  (void)S;
  float wr[4], wc[4];
  int kr[4], kc[4];
  mkw(step * i + koff, IMG, wr, kr);
  mkw(step * j + koff, IMG, wc, kc);
  float acc = 0.f;
#pragma unroll
  for (int u = 0; u < 4; ++u) {
    float rs = 0.f;
#pragma unroll
    for (int v = 0; v < 4; ++v) rs = fmaf(wc[v], src[kr[u] * IMG + kc[v]], rs);
    acc = fmaf(wr[u], rs, acc);
  }
  dst[oo] = acc;
}

// ---------------- K1: all patches from gray planes (fused Q pack) ------------------
// g in [0,16384): main scale -- s1 (x) AND s2 (gt) -> p1, p2c, Cp, Qp.
// g in [16384,20480): 96-scale; g in [20480,21504): 48-scale -> p2c, Cp.
__global__ void __launch_bounds__(256) patch_all_kernel(
    const float* __restrict__ gx, const float* __restrict__ ggt,
    const float* __restrict__ g96, const float* __restrict__ g48,
    float* __restrict__ p1, float* __restrict__ p2c,
    unsigned* __restrict__ Qp, unsigned* __restrict__ Cp) {
  int g = blockIdx.x * 256 + threadIdx.x;
  if (g < NROWS) {
    int b = g >> 12, p = g & (NP1 - 1);
    int hb = p >> 6, wb = p & 63;
    const int off = (hb * 3) * IMG + wb * 3;
    float gr[9];
    const float* gp = gx + (size_t)b * PL + off;
#pragma unroll
    for (int y = 0; y < 3; ++y)
#pragma unroll
      for (int xx = 0; xx < 3; ++xx) gr[y * 3 + xx] = gp[y * IMG + xx];
    float s1[27];
    float cs1;
    st_from_gray(gr, s1, cs1);
    store_row28(p1 + (size_t)g * RS, s1, cs1);

    const float* hp = ggt + (size_t)b * PL + off;
#pragma unroll
    for (int y = 0; y < 3; ++y)
#pragma unroll
      for (int xx = 0; xx < 3; ++xx) gr[y * 3 + xx] = hp[y * IMG + xx];
    float s2[27];
    float cs2;
    st_from_gray(gr, s2, cs2);
    size_t crow = (size_t)b * MALL + p;
    store_row28(p2c + crow * RS, s2, cs2);
    pack_row_frag(s2, -cs2, Cp + (crow >> 4) * 512, (int)(crow & 15));

    float q[27];
#pragma unroll
    for (int d = 0; d < 27; ++d) q[d] = s1[d] + s2[d];
    pack_row_frag(q, 1.0f, Qp + (size_t)(g >> 4) * 512, g & 15);
  } else {
    int q = g - NROWS;  // [0, 5120)
    const float* src;
    int S, row, hb, wb;
    if (q < BATCH * 1024) {
      int b = q >> 10, p = q & 1023;
      hb = p >> 5; wb = p & 31;
      src = g96 + (size_t)b * 9216;
      S = 96;
      row = b * MALL + NP1 + p;
    } else {
      int q2 = q - BATCH * 1024;
      int b = q2 >> 8, p = q2 & 255;
      hb = p >> 4; wb = p & 15;
      src = g48 + (size_t)b * 2304;
      S = 48;
      row = b * MALL + NP1 + 1024 + p;
    }
    float gr[9];
#pragma unroll
    for (int y = 0; y < 3; ++y)
#pragma unroll
      for (int xx = 0; xx < 3; ++xx) gr[y * 3 + xx] = src[(3 * hb + y) * S + 3 * wb + xx];
    float s[27];
    float cs;
    st_from_gray(gr, s, cs);
    store_row28(p2c + (size_t)row * RS, s, cs);
    pack_row_frag(s, -cs, Cp + ((size_t)row >> 4) * 512, row & 15);
  }
}

// ---------------- K3: MFMA argmax, LDS-staged C, 4 tiles per barrier round --------
// 256-thread blocks (4 waves); wave w owns 4 n-tiles (64 rows) -> 12 MFMAs per
// C-tile. All waves share C tiles via LDS: double-buffered 4-tile rounds (8 KB
// each), so only 2 barriers per 48 wave-MFMAs. Grid (16, NCHUNK=21, BATCH).
// D mapping (16x16x32): col=lane&15 (m), row=(lane>>4)*4+reg.
// key = (bits(score+4) & ~31) | (TPC-1-i); v_max_u32 running argmax; earlier tile
// wins ties => first-argmin after chunk combine. No launch_bounds occupancy cap.
__global__ void __launch_bounds__(256) argmin_mfma_kernel(
    const unsigned* __restrict__ Qp, const unsigned* __restrict__ Cp,
    unsigned* __restrict__ pkey, int* __restrict__ pidx) {
  const int lane = threadIdx.x & 63;
  const int w = threadIdx.x >> 6;
  const int td = threadIdx.x;
  const int chunk = blockIdx.y;
  const int b = blockIdx.z;
  const int nbase = blockIdx.x * 256 + w * 64;
  const int lm = lane & 15, lg = lane >> 4;

  __shared__ unsigned cbuf[2][RPT * 512];  // 2 x 8 KB

  bf16x8 qh[4], ql[4];
#pragma unroll
  for (int t = 0; t < 4; ++t) {
    const unsigned* tb = Qp + (size_t)((b * NP1 + nbase) >> 4) * 512 + (size_t)t * 512 + lane * 4;
    qh[t] = *reinterpret_cast<const bf16x8*>(tb);
    ql[t] = *reinterpret_cast<const bf16x8*>(tb + 256);
  }

  unsigned keys[4][4];
#pragma unroll
  for (int t = 0; t < 4; ++t)
#pragma unroll
    for (int r = 0; r < 4; ++r) keys[t][r] = 0u;

  const int tile0 = chunk * TPC;
  const unsigned* ct = Cp + (size_t)(b * (MALL >> 4) + tile0) * 512;

  // stage round 0 (4 tiles = 2048 uints; 8 uints / thread, coalesced)
  {
    uint4 a0 = *reinterpret_cast<const uint4*>(ct + 8 * td);
    uint4 a1 = *reinterpret_cast<const uint4*>(ct + 8 * td + 4);
    *reinterpret_cast<uint4*>(&cbuf[0][8 * td]) = a0;
    *reinterpret_cast<uint4*>(&cbuf[0][8 * td + 4]) = a1;
  }
  __syncthreads();

  for (int r = 0; r < ROUNDS; ++r) {
    uint4 n0, n1;
    if (r + 1 < ROUNDS) {  // issue next round's loads early (latency hides under MFMAs)
      n0 = *reinterpret_cast<const uint4*>(ct + (size_t)(r + 1) * (RPT * 512) + 8 * td);
      n1 = *reinterpret_cast<const uint4*>(ct + (size_t)(r + 1) * (RPT * 512) + 8 * td + 4);
    }
    const unsigned* cbr = &cbuf[r & 1][0];
#pragma unroll
    for (int it = 0; it < RPT; ++it) {
      const int i = r * RPT + it;
      bf16x8 ch = *reinterpret_cast<const bf16x8*>(cbr + it * 512 + lane * 4);
      bf16x8 cl = *reinterpret_cast<const bf16x8*>(cbr + it * 512 + 256 + lane * 4);
      const unsigned tag = (unsigned)(TPC - 1 - i);
#pragma unroll
      for (int t = 0; t < 4; ++t) {
        f32x4 a = {4.f, 4.f, 4.f, 4.f};  // +4 bias: scores positive
        a = __builtin_amdgcn_mfma_f32_16x16x32_bf16(qh[t], ch, a, 0, 0, 0);
        a = __builtin_amdgcn_mfma_f32_16x16x32_bf16(ql[t], ch, a, 0, 0, 0);
        a = __builtin_amdgcn_mfma_f32_16x16x32_bf16(qh[t], cl, a, 0, 0, 0);
#pragma unroll
        for (int rr = 0; rr < 4; ++rr) {
          unsigned kb = (__builtin_bit_cast(unsigned, (float)a[rr]) & 0xFFFFFFE0u) | tag;
          keys[t][rr] = keys[t][rr] > kb ? keys[t][rr] : kb;
        }
      }
    }
    if (r + 1 < ROUNDS) {
      __syncthreads();  // all waves done reading buf[(r+1)&1] (round r-1)
      *reinterpret_cast<uint4*>(&cbuf[(r + 1) & 1][8 * td]) = n0;
      *reinterpret_cast<uint4*>(&cbuf[(r + 1) & 1][8 * td + 4]) = n1;
      __syncthreads();  // writes visible before round r+1 reads
    }
  }

  // reduce (key, m) across the 16 lanes of each row-group; min m on key ties
#pragma unroll
  for (int t = 0; t < 4; ++t)
#pragma unroll
    for (int r = 0; r < 4; ++r) {
      unsigned k = keys[t][r];
      int m = (tile0 + (int)((unsigned)(TPC - 1) - (k & 31u))) * 16 + lm;
#pragma unroll
      for (int mk = 1; mk < 16; mk <<= 1) {
        unsigned ok = (unsigned)__shfl_xor((int)k, mk, 64);
        int om = __shfl_xor(m, mk, 64);
        bool take = (ok > k) || (ok == k && om < m);
        k = take ? ok : k;
        m = take ? om : m;
      }
      if (lm == 0) {
        int row = nbase + t * 16 + lg * 4 + r;
        size_t o = (size_t)chunk * NROWS + b * NP1 + row;  // [ms][g]: finalize coalesced
        pkey[o] = k & 0xFFFFFFE0u;  // masked: cross-chunk strict '>' keeps earliest chunk
        pidx[o] = m;
      }
    }
}

// ---------------- K4: combine partials, gather, L1 partials, ticketed final sum ---
__global__ void __launch_bounds__(256) finalize_kernel(
    const float* __restrict__ p1, const float* __restrict__ p2c,
    const unsigned* __restrict__ pkey, const int* __restrict__ pidx,
    float* __restrict__ bsum, unsigned* __restrict__ ctr, float* __restrict__ out) {
  int g = blockIdx.x * 256 + threadIdx.x;  // [0, NROWS)
  unsigned bk = 0u;
  int bi = 0;
  for (int ms = 0; ms < NCHUNK; ++ms) {
    unsigned k = pkey[(size_t)ms * NROWS + g];   // coalesced
    int ix = pidx[(size_t)ms * NROWS + g];
    bool gg = k > bk;  // strict > + ascending chunks => first-argmin tie-break
    bk = gg ? k : bk;
    bi = gg ? ix : bi;
  }
  int b = g >> 12;
  const float* a = p1 + (size_t)g * RS;
  const float* s2 = p2c + ((size_t)b * MALL + bi) * RS;
  float acc = 0.f;
#pragma unroll
  for (int d = 0; d < 27; ++d) acc += fabsf(a[d] - s2[d]);

  __shared__ float red[256];
  red[threadIdx.x] = acc;
  __syncthreads();
  for (int st = 128; st > 0; st >>= 1) {
    if (threadIdx.x < st) red[threadIdx.x] += red[threadIdx.x + st];
    __syncthreads();
  }
  if (threadIdx.x == 0) {
    __hip_atomic_store(&bsum[blockIdx.x], red[0], __ATOMIC_RELEASE, __HIP_MEMORY_SCOPE_AGENT);
    unsigned prev = __hip_atomic_fetch_add(ctr, 1u, __ATOMIC_ACQ_REL, __HIP_MEMORY_SCOPE_AGENT);
    if (prev == 63) {  // last of 64 blocks: deterministic ascending-order sum
      float s = 0.f;
      for (int i = 0; i < 64; ++i)
        s += __hip_atomic_load(&bsum[i], __ATOMIC_ACQUIRE, __HIP_MEMORY_SCOPE_AGENT);
      out[0] = s * (1.0f / 442368.0f);
    }
  }
}

}  // namespace

extern "C" void kernel_launch(void* const* d_in, const int* in_sizes, int n_in,
                              void* d_out, int out_size, void* d_ws, size_t ws_size,
                              hipStream_t stream) {
  const float* x  = (const float*)d_in[0];
  const float* gt = (const float*)d_in[1];
  float* out = (float*)d_out;

  // workspace layout (4-byte slots)
  float* ws = (float*)d_ws;
  float* p1   = ws;                                              // 458752
  float* p2c  = p1 + (size_t)BATCH * NP1 * RS;                   // 602112
  unsigned* Qp = (unsigned*)(p2c + (size_t)BATCH * MALL * RS);   // 524288
  unsigned* Cp = Qp + (size_t)BATCH * NP1 * 32;                  // 688128
  float* gx   = (float*)(Cp + (size_t)BATCH * MALL * 32);        // 147456
  float* ggt  = gx + (size_t)BATCH * PL;                         // 147456
  float* g96  = ggt + (size_t)BATCH * PL;                        // 36864
  float* g48  = g96 + (size_t)BATCH * 9216;                      // 9216
  unsigned* pkey = (unsigned*)(g48 + (size_t)BATCH * 2304);      // 21*16384
  int*   pidx   = (int*)(pkey + (size_t)NCHUNK * NROWS);         // 21*16384
  float* bsum   = (float*)(pidx + (size_t)NCHUNK * NROWS);       // 64
  unsigned* ctr = (unsigned*)(bsum + 64);                        // 1

  // K0: gray planes for x and gt (1152 blocks, coalesced)
  gray_kernel<<<(2 * BATCH * PL) / 256, 256, 0, stream>>>(x, gt, gx, ggt, ctr);

  // K0b: bicubic resize of gt gray plane -> g96, g48 (180 blocks)
  resize_gray_kernel<<<(BATCH * (9216 + 2304)) / 256, 256, 0, stream>>>(ggt, g96, g48);

  // K1: all patches from gray planes; fused Q pack (84 blocks)
  patch_all_kernel<<<(NROWS + BATCH * 1280) / 256, 256, 0, stream>>>(
      gx, ggt, g96, g48, p1, p2c, Qp, Cp);

  // K3: MFMA chunked argmax (LDS 4-tile rounds)
  {
    dim3 grid(16, NCHUNK, BATCH);
    argmin_mfma_kernel<<<grid, 256, 0, stream>>>(Qp, Cp, pkey, pidx);
  }

  // K4: combine chunks + L1 loss + ticketed deterministic final sum
  finalize_kernel<<<64, 256, 0, stream>>>(p1, p2c, pkey, pidx, bsum, ctr, out);
}

// Round 10
// 63.571 us; speedup vs baseline: 1.3200x; 1.3200x over previous
//
#include <hip/hip_runtime.h>
#include <hip/hip_bf16.h>
#include <math.h>

// ---------------- problem constants ----------------
namespace {
constexpr int BATCH = 4;
constexpr int IMG   = 192;
constexpr int PL    = IMG * IMG;   // 36864
constexpr int NP1   = 4096;   // 64*64 full-res patches per image
constexpr int MALL  = 5376;   // 4096 + 1024 + 256 candidate patches
constexpr int RS    = 28;     // fp32 row stride: 27 values + |c|^2 slot
constexpr int NCHUNK = 21;    // m-chunks for argmin partials
constexpr int TPC    = 16;    // 16-wide m-tiles per chunk (21*16*16 = 5376)
constexpr int RPT    = 2;     // tiles staged per barrier round
constexpr int ROUNDS = TPC / RPT;  // 8
constexpr int NROWS  = BATCH * NP1;  // 16384

// gaussian kernel constants (float32 images of the numpy float32 values)
#define GA 0.27406862f   // gauss1d(1.0) edge
#define GB 0.45186276f   // gauss1d(1.0) center
#define RC 0.33277732f   // gauss1d(10.0) edge
#define RD 0.33444537f   // gauss1d(10.0) center

typedef __bf16 bf16x8 __attribute__((ext_vector_type(8)));
typedef float  f32x4  __attribute__((ext_vector_type(4)));

__device__ __forceinline__ void conv3(const float in[9], const float k[9], float out[9]) {
#pragma unroll
  for (int y = 0; y < 3; ++y)
#pragma unroll
    for (int x = 0; x < 3; ++x) {
      float s = 0.f;
#pragma unroll
      for (int i = 0; i < 3; ++i) {
        int yy = y + i - 1;
        if (yy < 0 || yy > 2) continue;
#pragma unroll
        for (int j = 0; j < 3; ++j) {
          int xx = x + j - 1;
          if (xx < 0 || xx > 2) continue;
          s = fmaf(k[i * 3 + j], in[yy * 3 + xx], s);
        }
      }
      out[y * 3 + x] = s;
    }
}

// gray -> normalized structure-tensor 27-vector + |c|^2 of the normalized vec
__device__ __forceinline__ void st_from_gray(const float gray[9], float stv[27], float& cs) {
  const float KX[9] = {GA * GA, 0.f, -GA * GA, GB * GA, 0.f, -GB * GA, GA * GA, 0.f, -GA * GA};
  const float KY[9] = {GA * GA, GA * GB, GA * GA, 0.f, 0.f, 0.f, -GA * GA, -GA * GB, -GA * GA};
  const float KS[9] = {RC * RC, RC * RD, RC * RC, RD * RC, RD * RD, RD * RC, RC * RC, RC * RD, RC * RC};
  float Ix[9], Iy[9];
  conv3(gray, KX, Ix);
  conv3(gray, KY, Iy);
  float Pxx[9], Pyy[9], Pxy[9];
#pragma unroll
  for (int t = 0; t < 9; ++t) {
    Pxx[t] = Ix[t] * Ix[t];
    Pyy[t] = Iy[t] * Iy[t];
    Pxy[t] = Ix[t] * Iy[t];
  }
  conv3(Pxx, KS, stv + 0);
  conv3(Pyy, KS, stv + 9);
  conv3(Pxy, KS, stv + 18);
  float s2 = 0.f;
#pragma unroll
  for (int d = 0; d < 27; ++d) s2 = fmaf(stv[d], stv[d], s2);
  float inv = 1.0f / (sqrtf(s2) + 1e-12f);
  float c = 0.f;
#pragma unroll
  for (int d = 0; d < 27; ++d) {
    stv[d] *= inv;
    c = fmaf(stv[d], stv[d], c);
  }
  cs = c;
}

// ---------------- bicubic taps (jax.image.resize, antialias=False) ----------------
__device__ __forceinline__ void mkw(int k0, int IS, float w[4], int k[4]) {
  const float W4[4] = {-0.0625f, 0.5625f, 0.5625f, -0.0625f};
  float ssum = 0.f;
#pragma unroll
  for (int u = 0; u < 4; ++u) {
    int kk = k0 + u;
    bool v = (kk >= 0) && (kk < IS);
    w[u] = v ? W4[u] : 0.f;
    k[u] = v ? kk : 0;
    ssum += w[u];
  }
  float inv = 1.f / ssum;  // interior: exactly 1.0
#pragma unroll
  for (int u = 0; u < 4; ++u) w[u] *= inv;
}

// ---------------- fragment-major bf16 hi/lo pack ----------------
// Tile = 16 rows = 512 uints (2 KB): hi half uints 0..255, lo half 256..511.
// Row rl, k-group lg -> uint4 at (lg*16+rl)*4 (hi) / 256+(lg*16+rl)*4 (lo).
// In argmin, lane l reads uint4 at tile_base + l*4 -> fully coalesced.
__device__ __forceinline__ void pack_row_frag(const float* __restrict__ v, float tail,
                                              unsigned* __restrict__ base, int rl) {
  unsigned uh[16], ul[16];
#pragma unroll
  for (int p = 0; p < 16; ++p) {
    float a  = (2 * p < 27) ? v[2 * p] : 0.f;
    float bb = (2 * p + 1 < 27) ? v[2 * p + 1] : (2 * p + 1 == 27 ? tail : 0.f);
    __hip_bfloat16 ah = __float2bfloat16(a);
    __hip_bfloat16 bh = __float2bfloat16(bb);
    float af = __bfloat162float(ah), bf2 = __bfloat162float(bh);
    __hip_bfloat16 al = __float2bfloat16(a - af);
    __hip_bfloat16 bl = __float2bfloat16(bb - bf2);
    uh[p] = ((unsigned)__builtin_bit_cast(unsigned short, bh) << 16) |
            (unsigned)__builtin_bit_cast(unsigned short, ah);
    ul[p] = ((unsigned)__builtin_bit_cast(unsigned short, bl) << 16) |
            (unsigned)__builtin_bit_cast(unsigned short, al);
  }
#pragma unroll
  for (int lg = 0; lg < 4; ++lg) {
    *reinterpret_cast<uint4*>(base + (size_t)(lg * 16 + rl) * 4) =
        make_uint4(uh[4 * lg], uh[4 * lg + 1], uh[4 * lg + 2], uh[4 * lg + 3]);
    *reinterpret_cast<uint4*>(base + 256 + (size_t)(lg * 16 + rl) * 4) =
        make_uint4(ul[4 * lg], ul[4 * lg + 1], ul[4 * lg + 2], ul[4 * lg + 3]);
  }
}

__device__ __forceinline__ void store_row28(float* __restrict__ dst, const float v[27], float tail) {
  float4* d4 = reinterpret_cast<float4*>(dst);
#pragma unroll
  for (int i = 0; i < 6; ++i)
    d4[i] = make_float4(v[4 * i], v[4 * i + 1], v[4 * i + 2], v[4 * i + 3]);
  d4[6] = make_float4(v[24], v[25], v[26], tail);
}

// ---------------- K0: grayscale planes for x and gt (coalesced) ----------------
__global__ void __launch_bounds__(256) gray_kernel(
    const float* __restrict__ x, const float* __restrict__ gt,
    float* __restrict__ gx, float* __restrict__ ggt, unsigned* __restrict__ ctr) {
  int o = blockIdx.x * 256 + threadIdx.x;  // [0, 2*BATCH*PL)
  if (o == 0) ctr[0] = 0;                  // reset finalize ticket (stream-ordered)
  const float* src;
  float* dst;
  int oo;
  if (o < BATCH * PL) { src = x; dst = gx; oo = o; }
  else                { src = gt; dst = ggt; oo = o - BATCH * PL; }
  int b = oo / PL, p = oo - b * PL;
  const float* im = src + (size_t)b * 3 * PL;
  dst[oo] = fmaf(0.114f, im[2 * PL + p], fmaf(0.587f, im[PL + p], 0.2989f * im[p]));
}

// ---------------- K0b: bicubic resize of the gt gray plane (96 and 48) ------------
// Same tap order as the validated 3-channel path (gray commutes with resize).
__global__ void __launch_bounds__(256) resize_gray_kernel(
    const float* __restrict__ ggt, float* __restrict__ g96, float* __restrict__ g48) {
  int o = blockIdx.x * 256 + threadIdx.x;  // [0, 46080)
  int i, j, step, koff;
  const float* src;
  float* dst;
  int oo;
  if (o < BATCH * 9216) {
    int b = o / 9216, rem = o - b * 9216;
    i = rem / 96; j = rem - i * 96;
    step = 2; koff = -1;
    src = ggt + (size_t)b * PL;
    dst = g96; oo = o;
  } else {
    int q = o - BATCH * 9216;
    int b = q / 2304, rem = q - b * 2304;
    i = rem / 48; j = rem - i * 48;
    step = 4; koff = 0;
    src = ggt + (size_t)b * PL;
    dst = g48; oo = q;
  }
  float wr[4], wc[4];
  int kr[4], kc[4];
  mkw(step * i + koff, IMG, wr, kr);
  mkw(step * j + koff, IMG, wc, kc);
  float acc = 0.f;
#pragma unroll
  for (int u = 0; u < 4; ++u) {
    float rs = 0.f;
#pragma unroll
    for (int v = 0; v < 4; ++v) rs = fmaf(wc[v], src[kr[u] * IMG + kc[v]], rs);
    acc = fmaf(wr[u], rs, acc);
  }
  dst[oo] = acc;
}

// ---------------- K1: all patches; ONE st_from_gray per thread --------------------
// g in [0, 32768): main scale, lane-paired: even g -> x patch pid=g>>1, odd g -> gt
// patch pid. The 27-element s1 crosses to the gt lane via __shfl_xor(.,1), which
// then writes p2c + Cp AND the fused Qp pack (q = s1+s2). No thread holds two
// structure tensors plus pack temps -> no scratch spill (round-3/round-9 trap).
// g in [32768, 37888): scaled patches from g96/g48 gray planes -> p2c + Cp.
__global__ void __launch_bounds__(256) patch_all_kernel(
    const float* __restrict__ gx, const float* __restrict__ ggt,
    const float* __restrict__ g96, const float* __restrict__ g48,
    float* __restrict__ p1, float* __restrict__ p2c,
    unsigned* __restrict__ Qp, unsigned* __restrict__ Cp) {
  int g = blockIdx.x * 256 + threadIdx.x;
  if (g < 2 * NROWS) {
    const int pid = g >> 1;
    const bool isgt = g & 1;
    const int b = pid >> 12, p = pid & (NP1 - 1);
    const int hb = p >> 6, wb = p & 63;
    const float* src = (isgt ? ggt : gx) + (size_t)b * PL + (hb * 3) * IMG + wb * 3;
    float gr[9];
#pragma unroll
    for (int y = 0; y < 3; ++y)
#pragma unroll
      for (int xx = 0; xx < 3; ++xx) gr[y * 3 + xx] = src[y * IMG + xx];
    float s[27];
    float cs;
    st_from_gray(gr, s, cs);

    // pair exchange: even lane's s (=s1) -> odd lane; odd lane's s (=s2) -> even (unused)
    float o27[27];
#pragma unroll
    for (int d = 0; d < 27; ++d) o27[d] = __shfl_xor(s[d], 1, 64);

    if (!isgt) {
      store_row28(p1 + (size_t)pid * RS, s, cs);
    } else {
      size_t crow = (size_t)b * MALL + p;
      store_row28(p2c + crow * RS, s, cs);
      pack_row_frag(s, -cs, Cp + (crow >> 4) * 512, (int)(crow & 15));
      float q[27];
#pragma unroll
      for (int d = 0; d < 27; ++d) q[d] = s[d] + o27[d];
      pack_row_frag(q, 1.0f, Qp + (size_t)(pid >> 4) * 512, pid & 15);
    }
  } else {
    int q = g - 2 * NROWS;  // [0, 5120)
    const float* src;
    int S, row, hb, wb;
    if (q < BATCH * 1024) {
      int b = q >> 10, p = q & 1023;
      hb = p >> 5; wb = p & 31;
      src = g96 + (size_t)b * 9216;
      S = 96;
      row = b * MALL + NP1 + p;
    } else {
      int q2 = q - BATCH * 1024;
      int b = q2 >> 8, p = q2 & 255;
      hb = p >> 4; wb = p & 15;
      src = g48 + (size_t)b * 2304;
      S = 48;
      row = b * MALL + NP1 + 1024 + p;
    }
    float gr[9];
#pragma unroll
    for (int y = 0; y < 3; ++y)
#pragma unroll
      for (int xx = 0; xx < 3; ++xx) gr[y * 3 + xx] = src[(3 * hb + y) * S + 3 * wb + xx];
    float s[27];
    float cs;
    st_from_gray(gr, s, cs);
    store_row28(p2c + (size_t)row * RS, s, cs);
    pack_row_frag(s, -cs, Cp + ((size_t)row >> 4) * 512, row & 15);
  }
}

// ---------------- K3: MFMA argmax, LDS-staged C, round-8 structure, RPT=2 ---------
// 256-thread blocks (4 waves); wave owns 4 n-tiles (64 rows) -> 12 MFMAs/C-tile.
// Double-buffered 2-tile rounds (4 KB each): 2 barriers per 24 wave-MFMAs.
// Staging = uint2 x2 per thread (4 VGPRs). Target VGPR ~85 -> 6 waves/SIMD.
// Grid (16, NCHUNK=21, BATCH). key = (bits(score+4) & ~31) | (TPC-1-i).
__global__ void __launch_bounds__(256) argmin_mfma_kernel(
    const unsigned* __restrict__ Qp, const unsigned* __restrict__ Cp,
    unsigned* __restrict__ pkey, int* __restrict__ pidx) {
  const int lane = threadIdx.x & 63;
  const int w = threadIdx.x >> 6;
  const int td = threadIdx.x;
  const int chunk = blockIdx.y;
  const int b = blockIdx.z;
  const int nbase = blockIdx.x * 256 + w * 64;
  const int lm = lane & 15, lg = lane >> 4;

  __shared__ unsigned cbuf[2][RPT * 512];  // 2 x 4 KB

  bf16x8 qh[4], ql[4];
#pragma unroll
  for (int t = 0; t < 4; ++t) {
    const unsigned* tb = Qp + (size_t)((b * NP1 + nbase) >> 4) * 512 + (size_t)t * 512 + lane * 4;
    qh[t] = *reinterpret_cast<const bf16x8*>(tb);
    ql[t] = *reinterpret_cast<const bf16x8*>(tb + 256);
  }

  unsigned keys[4][4];
#pragma unroll
  for (int t = 0; t < 4; ++t)
#pragma unroll
    for (int r = 0; r < 4; ++r) keys[t][r] = 0u;

  const int tile0 = chunk * TPC;
  const unsigned* ct = Cp + (size_t)(b * (MALL >> 4) + tile0) * 512;

  // stage round 0 (2 tiles; uint2 per thread per tile, coalesced)
  {
    uint2 a0 = *reinterpret_cast<const uint2*>(ct + 2 * td);
    uint2 a1 = *reinterpret_cast<const uint2*>(ct + 512 + 2 * td);
    *reinterpret_cast<uint2*>(&cbuf[0][2 * td]) = a0;
    *reinterpret_cast<uint2*>(&cbuf[0][512 + 2 * td]) = a1;
  }
  __syncthreads();

  for (int r = 0; r < ROUNDS; ++r) {
    uint2 n0, n1;
    if (r + 1 < ROUNDS) {  // issue next round's loads at loop top: latency covered by MFMAs
      const unsigned* nt = ct + (size_t)(r + 1) * (RPT * 512);
      n0 = *reinterpret_cast<const uint2*>(nt + 2 * td);
      n1 = *reinterpret_cast<const uint2*>(nt + 512 + 2 * td);
    }
    const unsigned* cbr = &cbuf[r & 1][0];
#pragma unroll
    for (int it = 0; it < RPT; ++it) {
      const int i = r * RPT + it;
      bf16x8 ch = *reinterpret_cast<const bf16x8*>(cbr + it * 512 + lane * 4);
      bf16x8 cl = *reinterpret_cast<const bf16x8*>(cbr + it * 512 + 256 + lane * 4);
      const unsigned tag = (unsigned)(TPC - 1 - i);
#pragma unroll
      for (int t = 0; t < 4; ++t) {
        f32x4 a = {4.f, 4.f, 4.f, 4.f};  // +4 bias: scores positive
        a = __builtin_amdgcn_mfma_f32_16x16x32_bf16(qh[t], ch, a, 0, 0, 0);
        a = __builtin_amdgcn_mfma_f32_16x16x32_bf16(ql[t], ch, a, 0, 0, 0);
        a = __builtin_amdgcn_mfma_f32_16x16x32_bf16(qh[t], cl, a, 0, 0, 0);
#pragma unroll
        for (int rr = 0; rr < 4; ++rr) {
          unsigned kb = (__builtin_bit_cast(unsigned, (float)a[rr]) & 0xFFFFFFE0u) | tag;
          keys[t][rr] = keys[t][rr] > kb ? keys[t][rr] : kb;
        }
      }
    }
    if (r + 1 < ROUNDS) {
      __syncthreads();  // all waves done reading buf[(r+1)&1] (round r-1); vmcnt drain pre-covered
      *reinterpret_cast<uint2*>(&cbuf[(r + 1) & 1][2 * td]) = n0;
      *reinterpret_cast<uint2*>(&cbuf[(r + 1) & 1][512 + 2 * td]) = n1;
      __syncthreads();  // writes visible before round r+1 reads
    }
  }

  // reduce (key, m) across the 16 lanes of each row-group; min m on key ties
#pragma unroll
  for (int t = 0; t < 4; ++t)
#pragma unroll
    for (int r = 0; r < 4; ++r) {
      unsigned k = keys[t][r];
      int m = (tile0 + (int)((unsigned)(TPC - 1) - (k & 31u))) * 16 + lm;
#pragma unroll
      for (int mk = 1; mk < 16; mk <<= 1) {
        unsigned ok = (unsigned)__shfl_xor((int)k, mk, 64);
        int om = __shfl_xor(m, mk, 64);
        bool take = (ok > k) || (ok == k && om < m);
        k = take ? ok : k;
        m = take ? om : m;
      }
      if (lm == 0) {
        int row = nbase + t * 16 + lg * 4 + r;
        size_t o = (size_t)chunk * NROWS + b * NP1 + row;  // [ms][g]: finalize coalesced
        pkey[o] = k & 0xFFFFFFE0u;  // masked: cross-chunk strict '>' keeps earliest chunk
        pidx[o] = m;
      }
    }
}

// ---------------- K4: combine partials, gather, L1 partials, ticketed final sum ---
__global__ void __launch_bounds__(256) finalize_kernel(
    const float* __restrict__ p1, const float* __restrict__ p2c,
    const unsigned* __restrict__ pkey, const int* __restrict__ pidx,
    float* __restrict__ bsum, unsigned* __restrict__ ctr, float* __restrict__ out) {
  int g = blockIdx.x * 256 + threadIdx.x;  // [0, NROWS)
  unsigned bk = 0u;
  int bi = 0;
  for (int ms = 0; ms < NCHUNK; ++ms) {
    unsigned k = pkey[(size_t)ms * NROWS + g];   // coalesced
    int ix = pidx[(size_t)ms * NROWS + g];
    bool gg = k > bk;  // strict > + ascending chunks => first-argmin tie-break
    bk = gg ? k : bk;
    bi = gg ? ix : bi;
  }
  int b = g >> 12;
  const float* a = p1 + (size_t)g * RS;
  const float* s2 = p2c + ((size_t)b * MALL + bi) * RS;
  float acc = 0.f;
#pragma unroll
  for (int d = 0; d < 27; ++d) acc += fabsf(a[d] - s2[d]);

  __shared__ float red[256];
  red[threadIdx.x] = acc;
  __syncthreads();
  for (int st = 128; st > 0; st >>= 1) {
    if (threadIdx.x < st) red[threadIdx.x] += red[threadIdx.x + st];
    __syncthreads();
  }
  if (threadIdx.x == 0) {
    __hip_atomic_store(&bsum[blockIdx.x], red[0], __ATOMIC_RELEASE, __HIP_MEMORY_SCOPE_AGENT);
    unsigned prev = __hip_atomic_fetch_add(ctr, 1u, __ATOMIC_ACQ_REL, __HIP_MEMORY_SCOPE_AGENT);
    if (prev == 63) {  // last of 64 blocks: deterministic ascending-order sum
      float s = 0.f;
      for (int i = 0; i < 64; ++i)
        s += __hip_atomic_load(&bsum[i], __ATOMIC_ACQUIRE, __HIP_MEMORY_SCOPE_AGENT);
      out[0] = s * (1.0f / 442368.0f);
    }
  }
}

}  // namespace

extern "C" void kernel_launch(void* const* d_in, const int* in_sizes, int n_in,
                              void* d_out, int out_size, void* d_ws, size_t ws_size,
                              hipStream_t stream) {
  const float* x  = (const float*)d_in[0];
  const float* gt = (const float*)d_in[1];
  float* out = (float*)d_out;

  // workspace layout (4-byte slots)
  float* ws = (float*)d_ws;
  float* p1   = ws;                                              // 458752
  float* p2c  = p1 + (size_t)BATCH * NP1 * RS;                   // 602112
  unsigned* Qp = (unsigned*)(p2c + (size_t)BATCH * MALL * RS);   // 524288
  unsigned* Cp = Qp + (size_t)BATCH * NP1 * 32;                  // 688128
  float* gx   = (float*)(Cp + (size_t)BATCH * MALL * 32);        // 147456
  float* ggt  = gx + (size_t)BATCH * PL;                         // 147456
  float* g96  = ggt + (size_t)BATCH * PL;                        // 36864
  float* g48  = g96 + (size_t)BATCH * 9216;                      // 9216
  unsigned* pkey = (unsigned*)(g48 + (size_t)BATCH * 2304);      // 21*16384
  int*   pidx   = (int*)(pkey + (size_t)NCHUNK * NROWS);         // 21*16384
  float* bsum   = (float*)(pidx + (size_t)NCHUNK * NROWS);       // 64
  unsigned* ctr = (unsigned*)(bsum + 64);                        // 1

  // K0: gray planes for x and gt (1152 blocks, coalesced)
  gray_kernel<<<(2 * BATCH * PL) / 256, 256, 0, stream>>>(x, gt, gx, ggt, ctr);

  // K0b: bicubic resize of gt gray plane -> g96, g48 (180 blocks)
  resize_gray_kernel<<<(BATCH * (9216 + 2304)) / 256, 256, 0, stream>>>(ggt, g96, g48);

  // K1: all patches, one structure tensor per thread, lane-paired Q pack (148 blocks)
  patch_all_kernel<<<(2 * NROWS + BATCH * 1280) / 256, 256, 0, stream>>>(
      gx, ggt, g96, g48, p1, p2c, Qp, Cp);

  // K3: MFMA chunked argmax (round-8 structure, RPT=2)
  {
    dim3 grid(16, NCHUNK, BATCH);
    argmin_mfma_kernel<<<grid, 256, 0, stream>>>(Qp, Cp, pkey, pidx);
  }

  // K4: combine chunks + L1 loss + ticketed deterministic final sum
  finalize_kernel<<<64, 256, 0, stream>>>(p1, p2c, pkey, pidx, bsum, ctr, out);
}